// Round 9
// baseline (589.269 us; speedup 1.0000x reference)
//
#include <hip/hip_runtime.h>
#include <math.h>

#define L_SEQ 1024
#define NB 4
#define NH 16
#define DH 64
#define BH_TOT (NB * NH)            // 64
#define GQ_TOT (BH_TOT * L_SEQ)     // 65536
#define NPOS 257                    // 2*128+1
#define QP_STRIDE 260               // padded Qp row stride (u16 elements)
#define LDK 72                      // LDS K-stride (bf16) for attn tiles
#define LDQP 68                     // LDS stride for staged Qp slice (u16)
#define LDK32 40                    // LDS K-stride for gemm128 (BK=32 + pad)

typedef unsigned short ushort_t;
typedef __attribute__((ext_vector_type(8))) short bf16x8;
typedef __attribute__((ext_vector_type(4))) float f32x4;

__device__ inline ushort_t f2bf_rne(float x) {
    unsigned u = __float_as_uint(x);
    unsigned r = u + 0x7FFFu + ((u >> 16) & 1u);
    return (ushort_t)(r >> 16);
}
__device__ inline float bf2f(ushort_t h) {
    return __uint_as_float(((unsigned)h) << 16);
}
__device__ inline void split8(float4 a0, float4 a1, uint4* H, uint4* L) {
    float v[8] = {a0.x, a0.y, a0.z, a0.w, a1.x, a1.y, a1.z, a1.w};
    unsigned hh[4], ll[4];
    #pragma unroll
    for (int j = 0; j < 4; j++) {
        ushort_t h0 = f2bf_rne(v[2*j]),   h1 = f2bf_rne(v[2*j+1]);
        ushort_t l0 = f2bf_rne(v[2*j]   - bf2f(h0));
        ushort_t l1 = f2bf_rne(v[2*j+1] - bf2f(h1));
        hh[j] = (unsigned)h0 | ((unsigned)h1 << 16);
        ll[j] = (unsigned)l0 | ((unsigned)l1 << 16);
    }
    *H = (uint4){hh[0], hh[1], hh[2], hh[3]};
    *L = (uint4){ll[0], ll[1], ll[2], ll[3]};
}

// ---------------------------------------------------------------------------
// split_f32: A (fp32) -> hi/lo bf16 arrays. 8 elems/thread.
// ---------------------------------------------------------------------------
__global__ __launch_bounds__(256)
void split_f32(const float* __restrict__ A, ushort_t* __restrict__ hi,
               ushort_t* __restrict__ lo)
{
    const size_t base = ((size_t)blockIdx.x * 256 + threadIdx.x) * 8;
    uint4 H, L;
    split8(*(const float4*)(A + base), *(const float4*)(A + base + 4), &H, &L);
    *(uint4*)(hi + base) = H;
    *(uint4*)(lo + base) = L;
}

// ---------------------------------------------------------------------------
// split_transpose: W[K][N] fp32 -> Thi/Tlo[N][K] bf16 (64x64 tiles via LDS).
// ---------------------------------------------------------------------------
__global__ __launch_bounds__(256)
void split_transpose(const float* __restrict__ W, ushort_t* __restrict__ Thi,
                     ushort_t* __restrict__ Tlo, int Kdim, int Ndim)
{
    __shared__ float Ws[64][65];
    const int tid = threadIdx.x;
    const int k0 = blockIdx.x * 64;
    const int n0 = blockIdx.y * 64;
    const int r  = tid >> 4;
    const int c4 = (tid & 15) * 4;
    #pragma unroll
    for (int i = 0; i < 4; i++) {
        float4 v = *(const float4*)(W + (size_t)(k0 + r + i*16) * Ndim + n0 + c4);
        Ws[r + i*16][c4+0] = v.x;
        Ws[r + i*16][c4+1] = v.y;
        Ws[r + i*16][c4+2] = v.z;
        Ws[r + i*16][c4+3] = v.w;
    }
    __syncthreads();
    #pragma unroll
    for (int i = 0; i < 4; i++) {
        const int nl = r + i*16;
        ushort_t h[4], l[4];
        #pragma unroll
        for (int j = 0; j < 4; j++) {
            float x = Ws[c4 + j][nl];
            h[j] = f2bf_rne(x);
            l[j] = f2bf_rne(x - bf2f(h[j]));
        }
        size_t off = (size_t)(n0 + nl) * Kdim + k0 + c4;
        uint2 H, L;
        H.x = (unsigned)h[0] | ((unsigned)h[1] << 16);
        H.y = (unsigned)h[2] | ((unsigned)h[3] << 16);
        L.x = (unsigned)l[0] | ((unsigned)l[1] << 16);
        L.y = (unsigned)l[2] | ((unsigned)l[3] << 16);
        *(uint2*)(Thi + off) = H;
        *(uint2*)(Tlo + off) = L;
    }
}

// ---------------------------------------------------------------------------
// gemm_mfma128: C[M,N] = A @ B + bias, split-bf16 3-term MFMA, 128x128 tile.
// 4 waves (2x2), wave tile 64x64 = 4x4 MFMA 16x16x32. BK=32, 32 K-iters.
// Register prefetch of next K-slab hides global latency (grid == 1 block/CU).
// MFMA:ds_read = 48:16 per wave-iter (64-tile version was 24:16).
// mode 0: fp32 row-major; mode 1: bf16-hi u16 [B,H,L,DH]; mode 2: bf16-hi
// u16 V^T per head [B,H,DH,L].
// ---------------------------------------------------------------------------
__global__ __launch_bounds__(256)
void gemm_mfma128(const ushort_t* __restrict__ Ahi, const ushort_t* __restrict__ Alo,
                  const ushort_t* __restrict__ Bhi, const ushort_t* __restrict__ Blo,
                  const float* __restrict__ bias, void* __restrict__ Cout,
                  int M, int N, int K, int mode)
{
    __shared__ ushort_t As[2][128 * LDK32];
    __shared__ ushort_t Bs[2][128 * LDK32];
    const int tid  = threadIdx.x;
    const int m0   = blockIdx.x * 128;
    const int n0   = blockIdx.y * 128;
    const int wave = tid >> 6, lane = tid & 63;
    const int wr = wave >> 1, wc = wave & 1;
    const int lr = lane & 15, lq = lane >> 4;

    // staging slots: 512 uint4 per array per iter; 2 per thread
    const int s0 = tid,      r0 = s0 >> 2, c0 = (s0 & 3) * 8;
    const int s1 = 256 + tid,r1 = s1 >> 2, c1 = (s1 & 3) * 8;

    f32x4 acc[4][4];
    #pragma unroll
    for (int i = 0; i < 4; i++)
        #pragma unroll
        for (int j = 0; j < 4; j++)
            acc[i][j] = (f32x4){0.f, 0.f, 0.f, 0.f};

    uint4 pah0, pah1, pal0, pal1, pbh0, pbh1, pbl0, pbl1;
    // prologue: load k-slab 0
    {
        const size_t a0 = (size_t)(m0 + r0) * K + c0, a1 = (size_t)(m0 + r1) * K + c1;
        const size_t b0 = (size_t)(n0 + r0) * K + c0, b1 = (size_t)(n0 + r1) * K + c1;
        pah0 = *(const uint4*)(Ahi + a0); pah1 = *(const uint4*)(Ahi + a1);
        pal0 = *(const uint4*)(Alo + a0); pal1 = *(const uint4*)(Alo + a1);
        pbh0 = *(const uint4*)(Bhi + b0); pbh1 = *(const uint4*)(Bhi + b1);
        pbl0 = *(const uint4*)(Blo + b0); pbl1 = *(const uint4*)(Blo + b1);
    }

    const int iters = K >> 5;
    for (int it = 0; it < iters; it++) {
        __syncthreads();
        *(uint4*)&As[0][r0 * LDK32 + c0] = pah0;
        *(uint4*)&As[0][r1 * LDK32 + c1] = pah1;
        *(uint4*)&As[1][r0 * LDK32 + c0] = pal0;
        *(uint4*)&As[1][r1 * LDK32 + c1] = pal1;
        *(uint4*)&Bs[0][r0 * LDK32 + c0] = pbh0;
        *(uint4*)&Bs[0][r1 * LDK32 + c1] = pbh1;
        *(uint4*)&Bs[1][r0 * LDK32 + c0] = pbl0;
        *(uint4*)&Bs[1][r1 * LDK32 + c1] = pbl1;
        if (it + 1 < iters) {
            const int k0 = (it + 1) * 32;
            const size_t a0 = (size_t)(m0 + r0) * K + k0 + c0, a1 = (size_t)(m0 + r1) * K + k0 + c1;
            const size_t b0 = (size_t)(n0 + r0) * K + k0 + c0, b1 = (size_t)(n0 + r1) * K + k0 + c1;
            pah0 = *(const uint4*)(Ahi + a0); pah1 = *(const uint4*)(Ahi + a1);
            pal0 = *(const uint4*)(Alo + a0); pal1 = *(const uint4*)(Alo + a1);
            pbh0 = *(const uint4*)(Bhi + b0); pbh1 = *(const uint4*)(Bhi + b1);
            pbl0 = *(const uint4*)(Blo + b0); pbl1 = *(const uint4*)(Blo + b1);
        }
        __syncthreads();

        bf16x8 ah[4], al[4], bh[4], bl[4];
        #pragma unroll
        for (int i = 0; i < 4; i++) {
            const int ar = (wr*64 + i*16 + lr) * LDK32 + lq*8;
            ah[i] = *(const bf16x8*)&As[0][ar];
            al[i] = *(const bf16x8*)&As[1][ar];
            const int br = (wc*64 + i*16 + lr) * LDK32 + lq*8;
            bh[i] = *(const bf16x8*)&Bs[0][br];
            bl[i] = *(const bf16x8*)&Bs[1][br];
        }
        #pragma unroll
        for (int i = 0; i < 4; i++)
            #pragma unroll
            for (int j = 0; j < 4; j++) {
                acc[i][j] = __builtin_amdgcn_mfma_f32_16x16x32_bf16(ah[i], bh[j], acc[i][j], 0, 0, 0);
                acc[i][j] = __builtin_amdgcn_mfma_f32_16x16x32_bf16(ah[i], bl[j], acc[i][j], 0, 0, 0);
                acc[i][j] = __builtin_amdgcn_mfma_f32_16x16x32_bf16(al[i], bh[j], acc[i][j], 0, 0, 0);
            }
    }

    // epilogue: C-layout col = lane&15, row = quad*4 + reg
    #pragma unroll
    for (int j = 0; j < 4; j++) {
        const int colg = n0 + wc*64 + j*16 + lr;
        const float bcol = bias[colg];
        #pragma unroll
        for (int i = 0; i < 4; i++) {
            #pragma unroll
            for (int r = 0; r < 4; r++) {
                const int m = m0 + wr*64 + i*16 + lq*4 + r;
                const float v = acc[i][j][r] + bcol;
                if (mode == 0) {
                    ((float*)Cout)[(size_t)m * N + colg] = v;
                } else {
                    const int b = m >> 10, lp = m & 1023;
                    const int h = colg >> 6, dd = colg & 63;
                    const size_t off = (mode == 1)
                        ? ((size_t)(b * NH + h) * L_SEQ + lp) * DH + dd
                        : ((size_t)(b * NH + h) * DH + dd) * L_SEQ + lp;
                    ((ushort_t*)Cout)[off] = f2bf_rne(v);
                }
            }
        }
    }
}

// ---------------------------------------------------------------------------
// qp v5: Qp = Q @ posK^T (Q now bf16-hi u16), fp32 math, bf16 output.
// ---------------------------------------------------------------------------
__global__ __launch_bounds__(256)
void qp_kernel(const ushort_t* __restrict__ Qu, const float* __restrict__ posK,
               ushort_t* __restrict__ Qpu)
{
    __shared__ float Qt[64 * 64];
    __shared__ float Pt[64 * 64];
    const int tid = threadIdx.x;
    const size_t gq0 = (size_t)blockIdx.x * 64;
    const int ty = tid >> 4;
    const int tx = tid & 15;

    {
        const int q  = tid >> 2;
        const int d0 = (tid & 3) * 16;
        const ushort_t* qrow = Qu + (gq0 + q) * DH + d0;
        uint4 v0 = *(const uint4*)qrow;
        uint4 v1 = *(const uint4*)(qrow + 8);
        unsigned w[8] = {v0.x, v0.y, v0.z, v0.w, v1.x, v1.y, v1.z, v1.w};
        #pragma unroll
        for (int e = 0; e < 8; e++) {
            Qt[(d0 + 2*e + 0) * 64 + q] = bf2f((ushort_t)(w[e] & 0xffff));
            Qt[(d0 + 2*e + 1) * 64 + q] = bf2f((ushort_t)(w[e] >> 16));
        }
    }

    for (int c = 0; c < 4; c++) {
        __syncthreads();
        {
            const int r  = tid >> 2;
            const int d0 = (tid & 3) * 16;
            const float* krow = posK + (size_t)(c * 64 + r) * DH + d0;
            #pragma unroll
            for (int i = 0; i < 4; i++) {
                float4 v = *(const float4*)(krow + i * 4);
                Pt[(d0 + i*4 + 0) * 64 + r] = v.x;
                Pt[(d0 + i*4 + 1) * 64 + r] = v.y;
                Pt[(d0 + i*4 + 2) * 64 + r] = v.z;
                Pt[(d0 + i*4 + 3) * 64 + r] = v.w;
            }
        }
        __syncthreads();

        float acc[16];
        #pragma unroll
        for (int i = 0; i < 16; i++) acc[i] = 0.f;
        #pragma unroll 16
        for (int d = 0; d < 64; d++) {
            float4 qv = *(const float4*)&Qt[d * 64 + ty * 4];
            float4 pv = *(const float4*)&Pt[d * 64 + tx * 4];
            float qa[4] = {qv.x, qv.y, qv.z, qv.w};
            float pa[4] = {pv.x, pv.y, pv.z, pv.w};
            #pragma unroll
            for (int i = 0; i < 4; i++)
                #pragma unroll
                for (int j = 0; j < 4; j++)
                    acc[i * 4 + j] += qa[i] * pa[j];
        }
        #pragma unroll
        for (int i = 0; i < 4; i++) {
            uint2 o;
            o.x = (unsigned)f2bf_rne(acc[i*4+0]) | ((unsigned)f2bf_rne(acc[i*4+1]) << 16);
            o.y = (unsigned)f2bf_rne(acc[i*4+2]) | ((unsigned)f2bf_rne(acc[i*4+3]) << 16);
            *(uint2*)(Qpu + (gq0 + ty * 4 + i) * QP_STRIDE + c * 64 + tx * 4) = o;
        }
    }

    __syncthreads();
    if (tid < 64) {
        float s = 0.f;
        #pragma unroll 16
        for (int d = 0; d < 64; d++)
            s += Qt[d * 64 + tid] * posK[256 * 64 + d];
        Qpu[(gq0 + tid) * QP_STRIDE + 256] = f2bf_rne(s);
    }
}

// ---------------------------------------------------------------------------
// attn v7: Q/K/V^T arrive as bf16-hi u16 -> staging is pure uint4 copies
// (v6 spent ~160 VALU/thread-ktile re-packing the same fp32->bf16 values in
// every block). Everything else as v6: hi-only MFMA, LDS-staged Qp slice,
// 2-way k-split, bf16 p-band.
// ---------------------------------------------------------------------------
__global__ __launch_bounds__(256)
void attn_kernel(const ushort_t* __restrict__ Qu, const ushort_t* __restrict__ Ku,
                 const ushort_t* __restrict__ Vtu, const ushort_t* __restrict__ Qpu,
                 const float* __restrict__ pm,
                 ushort_t* __restrict__ SbandU,
                 float* __restrict__ O1a, float* __restrict__ O1b,
                 float* __restrict__ lsum2, float* __restrict__ clo2,
                 float* __restrict__ chi2)
{
    __shared__ ushort_t Qs[64 * LDK];     // Q-hi [q][d]
    __shared__ ushort_t KsPs[64 * LDK];   // K-hi [k][d]; re-used as P-hi [q][k]
    __shared__ ushort_t Vs[64 * LDK];     // V^T-hi [d][k]
    __shared__ ushort_t Qps[64 * LDQP];   // staged Qp slice [ql][kl] (bf16)
    __shared__ float mk[64];
    __shared__ float redl[128], redc[128], redh[128];

    const int tid = threadIdx.x;
    const int blk = blockIdx.x;
    const int bh  = blk >> 5;
    const int qb  = (blk >> 1) & 15;
    const int ks  = blk & 1;
    const int b   = bh >> 4;
    const int q0  = qb * 64;
    const size_t gq0 = (size_t)bh * L_SEQ + q0;
    const int wave = tid >> 6, lane = tid & 63;
    const int w0 = wave >> 1, w1 = wave & 1;
    const int lr = lane & 15, lq = lane >> 4;

    // stage Q tile (u16 copy)
    #pragma unroll
    for (int c = 0; c < 2; c++) {
        const int slot = c * 256 + tid;
        const int row = slot >> 3, col = (slot & 7) * 8;
        *(uint4*)&Qs[row * LDK + col] = *(const uint4*)(Qu + (gq0 + row) * DH + col);
    }

    // band zero-prefill for k outside [0,L) + pad col 255 (split 0 only)
    if (ks == 0 && tid < 64) {
        const int q = q0 + tid;
        ushort_t* bandRow = SbandU + (gq0 + tid) * 256;
        for (int j = 0; j < 127 - q; j++)    bandRow[j] = 0;
        for (int j = 254; j > 1150 - q; j--) bandRow[j] = 0;
        bandRow[255] = 0;
    }

    f32x4 Oacc[2][2];
    #pragma unroll
    for (int i = 0; i < 2; i++)
        #pragma unroll
        for (int j = 0; j < 2; j++)
            Oacc[i][j] = (f32x4){0.f, 0.f, 0.f, 0.f};
    float lpart[2][4] = {}, clpart[2][4] = {}, chpart[2][4] = {};

    const ushort_t* Kg  = Ku  + (size_t)bh * (L_SEQ * DH);
    const ushort_t* Vtg = Vtu + (size_t)bh * (DH * L_SEQ);

    for (int t = 0; t < 8; t++) {
        const int kt = ks * 8 + t;
        const int k0 = kt * 64;
        __syncthreads();   // prev O-pass done with KsPs/Vs/Qps

        // stage K [k][d], V^T [d][k] (u16 copies), Qp slice, mask
        #pragma unroll
        for (int c = 0; c < 2; c++) {
            const int slot = c * 256 + tid;
            const int row = slot >> 3, col = (slot & 7) * 8;
            const int la = row * LDK + col;
            *(uint4*)&KsPs[la] = *(const uint4*)(Kg + (size_t)(k0 + row) * DH + col);
            *(uint4*)&Vs[la]   = *(const uint4*)(Vtg + (size_t)row * L_SEQ + k0 + col);
        }
        // Qps[ql][kl] = Qp[gq0+ql][clip(k0+kl-q0-ql)+128]; coalesced along kl
        #pragma unroll
        for (int tt = 0; tt < 16; tt++) {
            const int idx = tt * 256 + tid;
            const int ql = idx >> 6, kl = idx & 63;
            int rel = k0 + kl - q0 - ql;
            rel = rel < -128 ? -128 : (rel > 128 ? 128 : rel);
            Qps[ql * LDQP + kl] = Qpu[(gq0 + ql) * QP_STRIDE + rel + 128];
        }
        if (tid < 64) mk[tid] = pm[b * L_SEQ + k0 + tid];
        __syncthreads();

        // S-pass MFMA (hi only)
        f32x4 Sacc[2][2];
        #pragma unroll
        for (int i = 0; i < 2; i++)
            #pragma unroll
            for (int j = 0; j < 2; j++)
                Sacc[i][j] = (f32x4){0.f, 0.f, 0.f, 0.f};
        #pragma unroll
        for (int kc = 0; kc < 2; kc++) {
            bf16x8 ah[2], bhf[2];
            #pragma unroll
            for (int i = 0; i < 2; i++) {
                ah[i]  = *(const bf16x8*)&Qs[(w0*32 + i*16 + lr) * LDK + kc*32 + lq*8];
                bhf[i] = *(const bf16x8*)&KsPs[(w1*32 + i*16 + lr) * LDK + kc*32 + lq*8];
            }
            #pragma unroll
            for (int i = 0; i < 2; i++)
                #pragma unroll
                for (int j = 0; j < 2; j++)
                    Sacc[i][j] = __builtin_amdgcn_mfma_f32_16x16x32_bf16(ah[i], bhf[j], Sacc[i][j], 0, 0, 0);
        }

        // epilogue: C-layout -> s, p, partials, band (bf16 p); Qp from LDS
        ushort_t pb[2][2][4];
        #pragma unroll
        for (int i = 0; i < 2; i++) {
            #pragma unroll
            for (int r = 0; r < 4; r++) {
                const int ql = w0*32 + i*16 + lq*4 + r;
                const int q  = q0 + ql;
                const size_t gq = gq0 + ql;
                ushort_t* bandRow = SbandU + gq * 256 + 127;
                #pragma unroll
                for (int j = 0; j < 2; j++) {
                    const int kl = w1*32 + j*16 + lr;
                    const int k  = k0 + kl;
                    const int rel = k - q;
                    float s = (Sacc[i][j][r] + bf2f(Qps[ql * LDQP + kl])) * 0.125f;
                    s *= mk[kl];
                    const float p = __expf(s);
                    lpart[i][r] += p;
                    const ushort_t ph = f2bf_rne(p);
                    if (rel <= -128)      clpart[i][r] += p;
                    else if (rel >= 128)  chpart[i][r] += p;
                    else                  bandRow[rel] = ph;
                    pb[i][j][r] = ph;
                }
            }
        }
        __syncthreads();   // all S-pass reads of KsPs done

        // write P-hi [q][k] over KsPs
        #pragma unroll
        for (int i = 0; i < 2; i++)
            #pragma unroll
            for (int j = 0; j < 2; j++)
                #pragma unroll
                for (int r = 0; r < 4; r++) {
                    const int ql = w0*32 + i*16 + lq*4 + r;
                    const int kl = w1*32 + j*16 + lr;
                    KsPs[ql * LDK + kl] = pb[i][j][r];
                }
        __syncthreads();

        // O-pass MFMA: O += P.V
        #pragma unroll
        for (int kc = 0; kc < 2; kc++) {
            bf16x8 pa[2], vh[2];
            #pragma unroll
            for (int i = 0; i < 2; i++) {
                pa[i] = *(const bf16x8*)&KsPs[(w0*32 + i*16 + lr) * LDK + kc*32 + lq*8];
                vh[i] = *(const bf16x8*)&Vs[(w1*32 + i*16 + lr) * LDK + kc*32 + lq*8];
            }
            #pragma unroll
            for (int i = 0; i < 2; i++)
                #pragma unroll
                for (int j = 0; j < 2; j++)
                    Oacc[i][j] = __builtin_amdgcn_mfma_f32_16x16x32_bf16(pa[i], vh[j], Oacc[i][j], 0, 0, 0);
        }
    }

    // reduce l/clo/chi across lr, then across the two w1 waves
    #pragma unroll
    for (int off = 1; off < 16; off <<= 1) {
        #pragma unroll
        for (int i = 0; i < 2; i++)
            #pragma unroll
            for (int r = 0; r < 4; r++) {
                lpart[i][r]  += __shfl_xor(lpart[i][r],  off, 64);
                clpart[i][r] += __shfl_xor(clpart[i][r], off, 64);
                chpart[i][r] += __shfl_xor(chpart[i][r], off, 64);
            }
    }
    if (lr == 0) {
        #pragma unroll
        for (int i = 0; i < 2; i++)
            #pragma unroll
            for (int r = 0; r < 4; r++) {
                const int ql = w0*32 + i*16 + lq*4 + r;
                redl[w1 * 64 + ql] = lpart[i][r];
                redc[w1 * 64 + ql] = clpart[i][r];
                redh[w1 * 64 + ql] = chpart[i][r];
            }
    }
    __syncthreads();
    if (tid < 64) {
        const size_t o = (size_t)ks * GQ_TOT + gq0 + tid;
        lsum2[o] = redl[tid] + redl[64 + tid];
        clo2[o]  = redc[tid] + redc[64 + tid];
        chi2[o]  = redh[tid] + redh[64 + tid];
    }

    // store O1 partial for this split
    float* O1o = ks ? O1b : O1a;
    #pragma unroll
    for (int i = 0; i < 2; i++)
        #pragma unroll
        for (int j = 0; j < 2; j++)
            #pragma unroll
            for (int r = 0; r < 4; r++) {
                const int ql = w0*32 + i*16 + lq*4 + r;
                const int dd = w1*32 + j*16 + lr;
                O1o[(gq0 + ql) * DH + dd] = Oacc[i][j][r];
            }
}

// ---------------------------------------------------------------------------
// Post v5: thread-per-q-row streaming GEMM over bf16 p-band; sums split
// partials; emits the attn matrix directly as bf16 hi/lo (A-side of the
// final GEMM) -- skips the fp32 round-trip + split_f32 pass.
// ---------------------------------------------------------------------------
__global__ __launch_bounds__(256)
void post_kernel(const ushort_t* __restrict__ SbandU,
                 const float* __restrict__ O1a, const float* __restrict__ O1b,
                 const float* __restrict__ lsum2, const float* __restrict__ clo2,
                 const float* __restrict__ chi2, const float* __restrict__ posV,
                 ushort_t* __restrict__ athi, ushort_t* __restrict__ atlo)
{
    __shared__ float Pl[256 * 33];
    __shared__ float pvs[32 * 64];
    const int tid = threadIdx.x;
    const size_t q0 = (size_t)blockIdx.x * 256;
    const size_t gq = q0 + tid;

    float acc[64];
    #pragma unroll
    for (int d = 0; d < 64; d++) acc[d] = 0.f;

    const ushort_t* bandBase = SbandU + q0 * 256;

    for (int c = 0; c < 8; c++) {
        const int rbase = c * 32;
        __syncthreads();
        #pragma unroll 1
        for (int i = 0; i < 32; i++) {
            int idx = i * 256 + tid;
            int row = idx >> 5;
            int j   = idx & 31;
            Pl[row * 33 + j] = bf2f(bandBase[(size_t)row * 256 + rbase + j]);
        }
        #pragma unroll
        for (int i = 0; i < 8; i++) {
            int e = i * 256 + tid;
            pvs[e] = posV[(rbase + 1) * 64 + e];
        }
        __syncthreads();
        #pragma unroll 1
        for (int j = 0; j < 32; j++) {
            float p = Pl[tid * 33 + j];
            const float4* pv = (const float4*)(pvs + j * 64);
            #pragma unroll
            for (int i = 0; i < 16; i++) {
                float4 v = pv[i];
                acc[4*i+0] += p * v.x;
                acc[4*i+1] += p * v.y;
                acc[4*i+2] += p * v.z;
                acc[4*i+3] += p * v.w;
            }
        }
    }

    const float li = lsum2[gq] + lsum2[GQ_TOT + gq];
    const float cl = clo2[gq]  + clo2[GQ_TOT + gq];
    const float ch = chi2[gq]  + chi2[GQ_TOT + gq];
    const float inv = 1.0f / li;
    const float4* o1A = (const float4*)(O1a + gq * DH);
    const float4* o1B = (const float4*)(O1b + gq * DH);
    const float4* pv0 = (const float4*)(posV);
    const float4* pvL = (const float4*)(posV + 256 * 64);
    const int b  = (int)(gq >> 14);
    const int h  = (int)((gq >> 10) & 15);
    const int lp = (int)(gq & 1023);
    const size_t obase = ((size_t)(b * L_SEQ + lp) * 1024) + h * 64;
    #pragma unroll
    for (int i = 0; i < 16; i++) {
        float4 a0 = o1A[i];
        float4 a1 = o1B[i];
        float4 z0 = pv0[i];
        float4 zL = pvL[i];
        float4 o;
        o.x = (a0.x + a1.x + acc[4*i+0] + cl * z0.x + ch * zL.x) * inv;
        o.y = (a0.y + a1.y + acc[4*i+1] + cl * z0.y + ch * zL.y) * inv;
        o.z = (a0.z + a1.z + acc[4*i+2] + cl * z0.z + ch * zL.z) * inv;
        o.w = (a0.w + a1.w + acc[4*i+3] + cl * z0.w + ch * zL.w) * inv;
        ushort_t h0 = f2bf_rne(o.x), h1 = f2bf_rne(o.y);
        ushort_t h2 = f2bf_rne(o.z), h3 = f2bf_rne(o.w);
        ushort_t l0 = f2bf_rne(o.x - bf2f(h0)), l1 = f2bf_rne(o.y - bf2f(h1));
        ushort_t l2 = f2bf_rne(o.z - bf2f(h2)), l3 = f2bf_rne(o.w - bf2f(h3));
        uint2 H = {(unsigned)h0 | ((unsigned)h1 << 16), (unsigned)h2 | ((unsigned)h3 << 16)};
        uint2 L = {(unsigned)l0 | ((unsigned)l1 << 16), (unsigned)l2 | ((unsigned)l3 << 16)};
        *(uint2*)(athi + obase + i * 4) = H;
        *(uint2*)(atlo + obase + i * 4) = L;
    }
}

// ---------------------------------------------------------------------------
extern "C" void kernel_launch(void* const* d_in, const int* in_sizes, int n_in,
                              void* d_out, int out_size, void* d_ws, size_t ws_size,
                              hipStream_t stream)
{
    const float* x    = (const float*)d_in[0];
    const float* pmk  = (const float*)d_in[1];
    const float* Wq   = (const float*)d_in[2];
    const float* bq   = (const float*)d_in[3];
    const float* Wk   = (const float*)d_in[4];
    const float* bk   = (const float*)d_in[5];
    const float* Wv   = (const float*)d_in[6];
    const float* bv   = (const float*)d_in[7];
    const float* Wo   = (const float*)d_in[8];
    const float* bo   = (const float*)d_in[9];
    const float* posK = (const float*)d_in[10];
    const float* posV = (const float*)d_in[11];
    float* out = (float*)d_out;

    // workspace carve-up (u16 units first, then f32)
    ushort_t* u = (ushort_t*)d_ws;
    ushort_t* Qbu    = u;                              // 4,194,304
    ushort_t* Kbu    = Qbu    + (size_t)GQ_TOT * DH;
    ushort_t* Vtu    = Kbu    + (size_t)GQ_TOT * DH;
    ushort_t* Qpu    = Vtu    + (size_t)GQ_TOT * DH;   // 65536*260
    ushort_t* SbandU = Qpu    + (size_t)GQ_TOT * QP_STRIDE;  // 65536*256
    ushort_t* athi   = SbandU + (size_t)GQ_TOT * 256;  // 4,194,304
    ushort_t* atlo   = athi   + (size_t)GQ_TOT * DH;
    float* fbase = (float*)(atlo + (size_t)GQ_TOT * DH);
    float* O1a   = fbase;
    float* O1b   = O1a   + (size_t)GQ_TOT * DH;
    float* lsum2 = O1b   + (size_t)GQ_TOT * DH;
    float* clo2  = lsum2 + 2 * (size_t)GQ_TOT;
    float* chi2  = clo2  + 2 * (size_t)GQ_TOT;

    // bf16 scratch aliased into the SbandU region (disjoint lifetimes):
    // phase A (x + QKV weight splits, consumed before attn writes bands):
    //   needs 14.68M u16 <= 16.78M region
    // phase B (Wo split, written after post reads bands): 2.1M u16
    ushort_t* bb   = SbandU;
    ushort_t* xhi  = bb;
    ushort_t* xlo  = xhi + 4194304;
    ushort_t* wqh  = xlo + 4194304;
    ushort_t* wql  = wqh + 1048576;
    ushort_t* wkh  = wql + 1048576;
    ushort_t* wkl  = wkh + 1048576;
    ushort_t* wvh  = wkl + 1048576;
    ushort_t* wvl  = wvh + 1048576;
    ushort_t* woh  = bb;
    ushort_t* wol  = woh + 1048576;

    dim3 tg(16, 16), gg128(32, 8), gb(256);

    split_f32<<<dim3(2048), gb, 0, stream>>>(x, xhi, xlo);
    split_transpose<<<tg, gb, 0, stream>>>(Wq, wqh, wql, 1024, 1024);
    split_transpose<<<tg, gb, 0, stream>>>(Wk, wkh, wkl, 1024, 1024);
    split_transpose<<<tg, gb, 0, stream>>>(Wv, wvh, wvl, 1024, 1024);
    gemm_mfma128<<<gg128, gb, 0, stream>>>(xhi, xlo, wqh, wql, bq, Qbu, 4096, 1024, 1024, 1);
    gemm_mfma128<<<gg128, gb, 0, stream>>>(xhi, xlo, wkh, wkl, bk, Kbu, 4096, 1024, 1024, 1);
    gemm_mfma128<<<gg128, gb, 0, stream>>>(xhi, xlo, wvh, wvl, bv, Vtu, 4096, 1024, 1024, 2);
    qp_kernel<<<dim3(GQ_TOT / 64), gb, 0, stream>>>(Qbu, posK, Qpu);
    attn_kernel<<<dim3(2048), gb, 0, stream>>>(Qbu, Kbu, Vtu, Qpu, pmk,
                                               SbandU, O1a, O1b, lsum2, clo2, chi2);
    post_kernel<<<dim3(GQ_TOT / 256), gb, 0, stream>>>(SbandU, O1a, O1b, lsum2,
                                                       clo2, chi2, posV, athi, atlo);
    split_transpose<<<tg, gb, 0, stream>>>(Wo, woh, wol, 1024, 1024);
    gemm_mfma128<<<gg128, gb, 0, stream>>>(athi, atlo, woh, wol, bo, out, 4096, 1024, 1024, 0);
}

// Round 10
// 439.648 us; speedup vs baseline: 1.3403x; 1.3403x over previous
//
#include <hip/hip_runtime.h>
#include <math.h>

#define L_SEQ 1024
#define NB 4
#define NH 16
#define DH 64
#define BH_TOT (NB * NH)            // 64
#define GQ_TOT (BH_TOT * L_SEQ)     // 65536
#define NPOS 257                    // 2*128+1
#define QP_STRIDE 260               // padded Qp row stride (u16 elements)
#define LDK 72                      // LDS K-stride (bf16) for attn/gemm tiles
#define LDQP 68                     // LDS stride for staged Qp slice (u16)
#define LDPV 264                    // pvT row stride (u16): word stride 132 ≡ 4 mod 32 -> 2-way reads

typedef unsigned short ushort_t;
typedef __attribute__((ext_vector_type(8))) short bf16x8;
typedef __attribute__((ext_vector_type(4))) float f32x4;

__device__ inline ushort_t f2bf_rne(float x) {
    unsigned u = __float_as_uint(x);
    unsigned r = u + 0x7FFFu + ((u >> 16) & 1u);
    return (ushort_t)(r >> 16);
}
__device__ inline float bf2f(ushort_t h) {
    return __uint_as_float(((unsigned)h) << 16);
}
__device__ inline void split8(float4 a0, float4 a1, uint4* H, uint4* L) {
    float v[8] = {a0.x, a0.y, a0.z, a0.w, a1.x, a1.y, a1.z, a1.w};
    unsigned hh[4], ll[4];
    #pragma unroll
    for (int j = 0; j < 4; j++) {
        ushort_t h0 = f2bf_rne(v[2*j]),   h1 = f2bf_rne(v[2*j+1]);
        ushort_t l0 = f2bf_rne(v[2*j]   - bf2f(h0));
        ushort_t l1 = f2bf_rne(v[2*j+1] - bf2f(h1));
        hh[j] = (unsigned)h0 | ((unsigned)h1 << 16);
        ll[j] = (unsigned)l0 | ((unsigned)l1 << 16);
    }
    *H = (uint4){hh[0], hh[1], hh[2], hh[3]};
    *L = (uint4){ll[0], ll[1], ll[2], ll[3]};
}
// 8 fp32 -> 8 bf16 (hi only). NOTE (R9 post-mortem): this pack VALU in attn's
// staging is not waste — it hides global-load latency between load and barrier.
// Replacing it with bare u16 copies regressed attn 137->218 us.
__device__ inline uint4 pack8hi(float4 a0, float4 a1) {
    float v[8] = {a0.x, a0.y, a0.z, a0.w, a1.x, a1.y, a1.z, a1.w};
    unsigned hh[4];
    #pragma unroll
    for (int j = 0; j < 4; j++)
        hh[j] = (unsigned)f2bf_rne(v[2*j]) | ((unsigned)f2bf_rne(v[2*j+1]) << 16);
    return (uint4){hh[0], hh[1], hh[2], hh[3]};
}

// ---------------------------------------------------------------------------
// split_f32: A (fp32) -> hi/lo bf16 arrays. 8 elems/thread.
// ---------------------------------------------------------------------------
__global__ __launch_bounds__(256)
void split_f32(const float* __restrict__ A, ushort_t* __restrict__ hi,
               ushort_t* __restrict__ lo)
{
    const size_t base = ((size_t)blockIdx.x * 256 + threadIdx.x) * 8;
    uint4 H, L;
    split8(*(const float4*)(A + base), *(const float4*)(A + base + 4), &H, &L);
    *(uint4*)(hi + base) = H;
    *(uint4*)(lo + base) = L;
}

// ---------------------------------------------------------------------------
// split_transpose: W[K][N] fp32 -> Thi/Tlo[N][K] bf16 (64x64 tiles via LDS).
// ---------------------------------------------------------------------------
__global__ __launch_bounds__(256)
void split_transpose(const float* __restrict__ W, ushort_t* __restrict__ Thi,
                     ushort_t* __restrict__ Tlo, int Kdim, int Ndim)
{
    __shared__ float Ws[64][65];
    const int tid = threadIdx.x;
    const int k0 = blockIdx.x * 64;
    const int n0 = blockIdx.y * 64;
    const int r  = tid >> 4;
    const int c4 = (tid & 15) * 4;
    #pragma unroll
    for (int i = 0; i < 4; i++) {
        float4 v = *(const float4*)(W + (size_t)(k0 + r + i*16) * Ndim + n0 + c4);
        Ws[r + i*16][c4+0] = v.x;
        Ws[r + i*16][c4+1] = v.y;
        Ws[r + i*16][c4+2] = v.z;
        Ws[r + i*16][c4+3] = v.w;
    }
    __syncthreads();
    #pragma unroll
    for (int i = 0; i < 4; i++) {
        const int nl = r + i*16;
        ushort_t h[4], l[4];
        #pragma unroll
        for (int j = 0; j < 4; j++) {
            float x = Ws[c4 + j][nl];
            h[j] = f2bf_rne(x);
            l[j] = f2bf_rne(x - bf2f(h[j]));
        }
        size_t off = (size_t)(n0 + nl) * Kdim + k0 + c4;
        uint2 H, L;
        H.x = (unsigned)h[0] | ((unsigned)h[1] << 16);
        H.y = (unsigned)h[2] | ((unsigned)h[3] << 16);
        L.x = (unsigned)l[0] | ((unsigned)l[1] << 16);
        L.y = (unsigned)l[2] | ((unsigned)l[3] << 16);
        *(uint2*)(Thi + off) = H;
        *(uint2*)(Tlo + off) = L;
    }
}

// ---------------------------------------------------------------------------
// prep_pvt: posV fp32 [257][64] -> global pvT bf16 [64 d][LDPV r], r=0..255
// maps posV rows 1..256. 4 blocks, one 64-r chunk each.
// ---------------------------------------------------------------------------
__global__ __launch_bounds__(256)
void prep_pvt(const float* __restrict__ posV, ushort_t* __restrict__ pvTg)
{
    __shared__ float Ws[64][65];
    const int tid = threadIdx.x;
    const int c = blockIdx.x;            // r-chunk 0..3
    {
        const int r  = tid >> 2;
        const int d0 = (tid & 3) * 16;
        const float* src = posV + (size_t)(c * 64 + r + 1) * 64 + d0;
        #pragma unroll
        for (int i = 0; i < 4; i++) {
            float4 v = *(const float4*)(src + i * 4);
            Ws[r][d0 + i*4 + 0] = v.x;
            Ws[r][d0 + i*4 + 1] = v.y;
            Ws[r][d0 + i*4 + 2] = v.z;
            Ws[r][d0 + i*4 + 3] = v.w;
        }
    }
    __syncthreads();
    {
        const int d  = tid >> 2;
        const int r0 = (tid & 3) * 16;
        #pragma unroll
        for (int k = 0; k < 16; k++)
            pvTg[(size_t)d * LDPV + c * 64 + r0 + k] = f2bf_rne(Ws[r0 + k][d]);
    }
}

// ---------------------------------------------------------------------------
// gemm_mfma (R8-proven 64-tile): C = A @ B + bias, split-bf16 3-term MFMA.
// mode 0: fp32 row-major; mode 1: fp32 [B,H,L,DH]; mode 2: fp32 V^T [B,H,DH,L].
// ---------------------------------------------------------------------------
__global__ __launch_bounds__(256)
void gemm_mfma(const ushort_t* __restrict__ Ahi, const ushort_t* __restrict__ Alo,
               const ushort_t* __restrict__ Bhi, const ushort_t* __restrict__ Blo,
               const float* __restrict__ bias, float* __restrict__ C,
               int M, int N, int K, int mode)
{
    __shared__ ushort_t As[2][64 * LDK];
    __shared__ ushort_t Bs[2][64 * LDK];
    const int tid  = threadIdx.x;
    const int m0   = blockIdx.x * 64;
    const int n0   = blockIdx.y * 64;
    const int wave = tid >> 6;
    const int lane = tid & 63;
    const int w0 = wave >> 1;
    const int w1 = wave & 1;
    const int lr = lane & 15;
    const int lq = lane >> 4;

    f32x4 acc[2][2];
    #pragma unroll
    for (int i = 0; i < 2; i++)
        #pragma unroll
        for (int j = 0; j < 2; j++)
            acc[i][j] = (f32x4){0.f, 0.f, 0.f, 0.f};

    for (int k0 = 0; k0 < K; k0 += 64) {
        __syncthreads();
        #pragma unroll
        for (int c = 0; c < 2; c++) {
            const int n   = c * 256 + tid;
            const int row = n >> 3;
            const int col = (n & 7) * 8;
            const size_t ga = (size_t)(m0 + row) * K + k0 + col;
            const size_t gb = (size_t)(n0 + row) * K + k0 + col;
            const int la = row * LDK + col;
            *(uint4*)&As[0][la] = *(const uint4*)(Ahi + ga);
            *(uint4*)&As[1][la] = *(const uint4*)(Alo + ga);
            *(uint4*)&Bs[0][la] = *(const uint4*)(Bhi + gb);
            *(uint4*)&Bs[1][la] = *(const uint4*)(Blo + gb);
        }
        __syncthreads();
        #pragma unroll
        for (int ks = 0; ks < 2; ks++) {
            bf16x8 ah[2], al[2], bh[2], bl[2];
            #pragma unroll
            for (int i = 0; i < 2; i++) {
                const int ar = (w0*32 + i*16 + lr) * LDK + ks*32 + lq*8;
                ah[i] = *(const bf16x8*)&As[0][ar];
                al[i] = *(const bf16x8*)&As[1][ar];
                const int br = (w1*32 + i*16 + lr) * LDK + ks*32 + lq*8;
                bh[i] = *(const bf16x8*)&Bs[0][br];
                bl[i] = *(const bf16x8*)&Bs[1][br];
            }
            #pragma unroll
            for (int i = 0; i < 2; i++)
                #pragma unroll
                for (int j = 0; j < 2; j++) {
                    acc[i][j] = __builtin_amdgcn_mfma_f32_16x16x32_bf16(ah[i], bh[j], acc[i][j], 0, 0, 0);
                    acc[i][j] = __builtin_amdgcn_mfma_f32_16x16x32_bf16(ah[i], bl[j], acc[i][j], 0, 0, 0);
                    acc[i][j] = __builtin_amdgcn_mfma_f32_16x16x32_bf16(al[i], bh[j], acc[i][j], 0, 0, 0);
                }
        }
    }

    #pragma unroll
    for (int j = 0; j < 2; j++) {
        const int colg = n0 + w1*32 + j*16 + lr;
        const float bcol = bias[colg];
        #pragma unroll
        for (int i = 0; i < 2; i++) {
            #pragma unroll
            for (int r = 0; r < 4; r++) {
                const int m = m0 + w0*32 + i*16 + lq*4 + r;
                const float v = acc[i][j][r] + bcol;
                if (mode == 0) {
                    C[(size_t)m * N + colg] = v;
                } else if (mode == 1) {
                    const int b = m >> 10, lp = m & 1023;
                    const int h = colg >> 6, dd = colg & 63;
                    C[((size_t)(b * NH + h) * L_SEQ + lp) * DH + dd] = v;
                } else {
                    const int b = m >> 10, lp = m & 1023;
                    const int h = colg >> 6, dd = colg & 63;
                    C[((size_t)(b * NH + h) * DH + dd) * L_SEQ + lp] = v;
                }
            }
        }
    }
}

// ---------------------------------------------------------------------------
// qp v4 (R8-proven): Qp = Q @ posK^T, fp32 math, bf16 output.
// ---------------------------------------------------------------------------
__global__ __launch_bounds__(256)
void qp_kernel(const float* __restrict__ Q, const float* __restrict__ posK,
               ushort_t* __restrict__ Qpu)
{
    __shared__ float Qt[64 * 64];
    __shared__ float Pt[64 * 64];
    const int tid = threadIdx.x;
    const size_t gq0 = (size_t)blockIdx.x * 64;
    const int ty = tid >> 4;
    const int tx = tid & 15;

    {
        const int q  = tid >> 2;
        const int d0 = (tid & 3) * 16;
        const float* qrow = Q + (gq0 + q) * DH + d0;
        #pragma unroll
        for (int i = 0; i < 4; i++) {
            float4 v = *(const float4*)(qrow + i * 4);
            Qt[(d0 + i*4 + 0) * 64 + q] = v.x;
            Qt[(d0 + i*4 + 1) * 64 + q] = v.y;
            Qt[(d0 + i*4 + 2) * 64 + q] = v.z;
            Qt[(d0 + i*4 + 3) * 64 + q] = v.w;
        }
    }

    for (int c = 0; c < 4; c++) {
        __syncthreads();
        {
            const int r  = tid >> 2;
            const int d0 = (tid & 3) * 16;
            const float* krow = posK + (size_t)(c * 64 + r) * DH + d0;
            #pragma unroll
            for (int i = 0; i < 4; i++) {
                float4 v = *(const float4*)(krow + i * 4);
                Pt[(d0 + i*4 + 0) * 64 + r] = v.x;
                Pt[(d0 + i*4 + 1) * 64 + r] = v.y;
                Pt[(d0 + i*4 + 2) * 64 + r] = v.z;
                Pt[(d0 + i*4 + 3) * 64 + r] = v.w;
            }
        }
        __syncthreads();

        float acc[16];
        #pragma unroll
        for (int i = 0; i < 16; i++) acc[i] = 0.f;
        #pragma unroll 16
        for (int d = 0; d < 64; d++) {
            float4 qv = *(const float4*)&Qt[d * 64 + ty * 4];
            float4 pv = *(const float4*)&Pt[d * 64 + tx * 4];
            float qa[4] = {qv.x, qv.y, qv.z, qv.w};
            float pa[4] = {pv.x, pv.y, pv.z, pv.w};
            #pragma unroll
            for (int i = 0; i < 4; i++)
                #pragma unroll
                for (int j = 0; j < 4; j++)
                    acc[i * 4 + j] += qa[i] * pa[j];
        }
        #pragma unroll
        for (int i = 0; i < 4; i++) {
            uint2 o;
            o.x = (unsigned)f2bf_rne(acc[i*4+0]) | ((unsigned)f2bf_rne(acc[i*4+1]) << 16);
            o.y = (unsigned)f2bf_rne(acc[i*4+2]) | ((unsigned)f2bf_rne(acc[i*4+3]) << 16);
            *(uint2*)(Qpu + (gq0 + ty * 4 + i) * QP_STRIDE + c * 64 + tx * 4) = o;
        }
    }

    __syncthreads();
    if (tid < 64) {
        float s = 0.f;
        #pragma unroll 16
        for (int d = 0; d < 64; d++)
            s += Qt[d * 64 + tid] * posK[256 * 64 + d];
        Qpu[(gq0 + tid) * QP_STRIDE + 256] = f2bf_rne(s);
    }
}

// ---------------------------------------------------------------------------
// attn v6 (R8-proven, 137 us): fp32 Q/K/V^T inputs + pack8hi staging (the
// pack VALU hides load latency — see R9 post-mortem), hi-only MFMA,
// LDS-staged Qp slice, 2-way k-split, bf16 p-band.
// ---------------------------------------------------------------------------
__global__ __launch_bounds__(256)
void attn_kernel(const float* __restrict__ Q, const float* __restrict__ K,
                 const float* __restrict__ Vt, const ushort_t* __restrict__ Qpu,
                 const float* __restrict__ pm,
                 ushort_t* __restrict__ SbandU,
                 float* __restrict__ O1a, float* __restrict__ O1b,
                 float* __restrict__ lsum2, float* __restrict__ clo2,
                 float* __restrict__ chi2)
{
    __shared__ ushort_t Qs[64 * LDK];     // Q-hi [q][d]
    __shared__ ushort_t KsPs[64 * LDK];   // K-hi [k][d]; re-used as P-hi [q][k]
    __shared__ ushort_t Vs[64 * LDK];     // V^T-hi [d][k]
    __shared__ ushort_t Qps[64 * LDQP];   // staged Qp slice [ql][kl] (bf16)
    __shared__ float mk[64];
    __shared__ float redl[128], redc[128], redh[128];

    const int tid = threadIdx.x;
    const int blk = blockIdx.x;
    const int bh  = blk >> 5;
    const int qb  = (blk >> 1) & 15;
    const int ks  = blk & 1;
    const int b   = bh >> 4;
    const int q0  = qb * 64;
    const size_t gq0 = (size_t)bh * L_SEQ + q0;
    const int wave = tid >> 6, lane = tid & 63;
    const int w0 = wave >> 1, w1 = wave & 1;
    const int lr = lane & 15, lq = lane >> 4;

    // stage Q tile (bf16 hi)
    #pragma unroll
    for (int c = 0; c < 2; c++) {
        const int slot = c * 256 + tid;
        const int row = slot >> 3, col = (slot & 7) * 8;
        const float* src = Q + (gq0 + row) * DH + col;
        *(uint4*)&Qs[row * LDK + col] =
            pack8hi(*(const float4*)src, *(const float4*)(src + 4));
    }

    // band zero-prefill for k outside [0,L) + pad col 255 (split 0 only)
    if (ks == 0 && tid < 64) {
        const int q = q0 + tid;
        ushort_t* bandRow = SbandU + (gq0 + tid) * 256;
        for (int j = 0; j < 127 - q; j++)    bandRow[j] = 0;
        for (int j = 254; j > 1150 - q; j--) bandRow[j] = 0;
        bandRow[255] = 0;
    }

    f32x4 Oacc[2][2];
    #pragma unroll
    for (int i = 0; i < 2; i++)
        #pragma unroll
        for (int j = 0; j < 2; j++)
            Oacc[i][j] = (f32x4){0.f, 0.f, 0.f, 0.f};
    float lpart[2][4] = {}, clpart[2][4] = {}, chpart[2][4] = {};

    const float* Kg  = K  + (size_t)bh * (L_SEQ * DH);
    const float* Vtg = Vt + (size_t)bh * (DH * L_SEQ);

    for (int t = 0; t < 8; t++) {
        const int kt = ks * 8 + t;
        const int k0 = kt * 64;
        __syncthreads();   // prev O-pass done with KsPs/Vs/Qps

        // stage K [k][d], V^T [d][k] (pack fp32 -> bf16 hi), Qp slice, mask
        #pragma unroll
        for (int c = 0; c < 2; c++) {
            const int slot = c * 256 + tid;
            const int row = slot >> 3, col = (slot & 7) * 8;
            const int la = row * LDK + col;
            const float* ksrc = Kg + (size_t)(k0 + row) * DH + col;
            *(uint4*)&KsPs[la] =
                pack8hi(*(const float4*)ksrc, *(const float4*)(ksrc + 4));
            const float* vsrc = Vtg + (size_t)row * L_SEQ + k0 + col;
            *(uint4*)&Vs[la] =
                pack8hi(*(const float4*)vsrc, *(const float4*)(vsrc + 4));
        }
        // Qps[ql][kl] = Qp[gq0+ql][clip(k0+kl-q0-ql)+128]; coalesced along kl
        #pragma unroll
        for (int tt = 0; tt < 16; tt++) {
            const int idx = tt * 256 + tid;
            const int ql = idx >> 6, kl = idx & 63;
            int rel = k0 + kl - q0 - ql;
            rel = rel < -128 ? -128 : (rel > 128 ? 128 : rel);
            Qps[ql * LDQP + kl] = Qpu[(gq0 + ql) * QP_STRIDE + rel + 128];
        }
        if (tid < 64) mk[tid] = pm[b * L_SEQ + k0 + tid];
        __syncthreads();

        // S-pass MFMA (hi only)
        f32x4 Sacc[2][2];
        #pragma unroll
        for (int i = 0; i < 2; i++)
            #pragma unroll
            for (int j = 0; j < 2; j++)
                Sacc[i][j] = (f32x4){0.f, 0.f, 0.f, 0.f};
        #pragma unroll
        for (int kc = 0; kc < 2; kc++) {
            bf16x8 ah[2], bhf[2];
            #pragma unroll
            for (int i = 0; i < 2; i++) {
                ah[i]  = *(const bf16x8*)&Qs[(w0*32 + i*16 + lr) * LDK + kc*32 + lq*8];
                bhf[i] = *(const bf16x8*)&KsPs[(w1*32 + i*16 + lr) * LDK + kc*32 + lq*8];
            }
            #pragma unroll
            for (int i = 0; i < 2; i++)
                #pragma unroll
                for (int j = 0; j < 2; j++)
                    Sacc[i][j] = __builtin_amdgcn_mfma_f32_16x16x32_bf16(ah[i], bhf[j], Sacc[i][j], 0, 0, 0);
        }

        // epilogue: C-layout -> s, p, partials, band (bf16 p); Qp from LDS
        ushort_t pb[2][2][4];
        #pragma unroll
        for (int i = 0; i < 2; i++) {
            #pragma unroll
            for (int r = 0; r < 4; r++) {
                const int ql = w0*32 + i*16 + lq*4 + r;
                const int q  = q0 + ql;
                const size_t gq = gq0 + ql;
                ushort_t* bandRow = SbandU + gq * 256 + 127;
                #pragma unroll
                for (int j = 0; j < 2; j++) {
                    const int kl = w1*32 + j*16 + lr;
                    const int k  = k0 + kl;
                    const int rel = k - q;
                    float s = (Sacc[i][j][r] + bf2f(Qps[ql * LDQP + kl])) * 0.125f;
                    s *= mk[kl];
                    const float p = __expf(s);
                    lpart[i][r] += p;
                    const ushort_t ph = f2bf_rne(p);
                    if (rel <= -128)      clpart[i][r] += p;
                    else if (rel >= 128)  chpart[i][r] += p;
                    else                  bandRow[rel] = ph;
                    pb[i][j][r] = ph;
                }
            }
        }
        __syncthreads();   // all S-pass reads of KsPs done

        // write P-hi [q][k] over KsPs
        #pragma unroll
        for (int i = 0; i < 2; i++)
            #pragma unroll
            for (int j = 0; j < 2; j++)
                #pragma unroll
                for (int r = 0; r < 4; r++) {
                    const int ql = w0*32 + i*16 + lq*4 + r;
                    const int kl = w1*32 + j*16 + lr;
                    KsPs[ql * LDK + kl] = pb[i][j][r];
                }
        __syncthreads();

        // O-pass MFMA: O += P.V
        #pragma unroll
        for (int kc = 0; kc < 2; kc++) {
            bf16x8 pa[2], vh[2];
            #pragma unroll
            for (int i = 0; i < 2; i++) {
                pa[i] = *(const bf16x8*)&KsPs[(w0*32 + i*16 + lr) * LDK + kc*32 + lq*8];
                vh[i] = *(const bf16x8*)&Vs[(w1*32 + i*16 + lr) * LDK + kc*32 + lq*8];
            }
            #pragma unroll
            for (int i = 0; i < 2; i++)
                #pragma unroll
                for (int j = 0; j < 2; j++)
                    Oacc[i][j] = __builtin_amdgcn_mfma_f32_16x16x32_bf16(pa[i], vh[j], Oacc[i][j], 0, 0, 0);
        }
    }

    // reduce l/clo/chi across lr, then across the two w1 waves
    #pragma unroll
    for (int off = 1; off < 16; off <<= 1) {
        #pragma unroll
        for (int i = 0; i < 2; i++)
            #pragma unroll
            for (int r = 0; r < 4; r++) {
                lpart[i][r]  += __shfl_xor(lpart[i][r],  off, 64);
                clpart[i][r] += __shfl_xor(clpart[i][r], off, 64);
                chpart[i][r] += __shfl_xor(chpart[i][r], off, 64);
            }
    }
    if (lr == 0) {
        #pragma unroll
        for (int i = 0; i < 2; i++)
            #pragma unroll
            for (int r = 0; r < 4; r++) {
                const int ql = w0*32 + i*16 + lq*4 + r;
                redl[w1 * 64 + ql] = lpart[i][r];
                redc[w1 * 64 + ql] = clpart[i][r];
                redh[w1 * 64 + ql] = chpart[i][r];
            }
    }
    __syncthreads();
    if (tid < 64) {
        const size_t o = (size_t)ks * GQ_TOT + gq0 + tid;
        lsum2[o] = redl[tid] + redl[64 + tid];
        clo2[o]  = redc[tid] + redc[64 + tid];
        chi2[o]  = redh[tid] + redh[64 + tid];
    }

    // store O1 partial for this split
    float* O1o = ks ? O1b : O1a;
    #pragma unroll
    for (int i = 0; i < 2; i++)
        #pragma unroll
        for (int j = 0; j < 2; j++)
            #pragma unroll
            for (int r = 0; r < 4; r++) {
                const int ql = w0*32 + i*16 + lq*4 + r;
                const int dd = w1*32 + j*16 + lr;
                O1o[(gq0 + ql) * DH + dd] = Oacc[i][j][r];
            }
}

// ---------------------------------------------------------------------------
// post_mfma: O2[64q x 64d] = band[64 x 256 bf16] @ posV^T via MFMA.
// A-frags read DIRECTLY from global band (16B/lane, no k-loop barriers ->
// pipelineable); B-frags from LDS copy of prepped pvT. Epilogue fuses
// O1a+O1b+clamped terms, 1/l, and emits athi/atlo bf16 split directly.
// Replaces the scalar-VALU post (2.14 GFLOP at ~13.6us VALU floor but ~55us
// measured) with ~128 MFMAs/block. Grid 1024.
// ---------------------------------------------------------------------------
__global__ __launch_bounds__(256)
void post_mfma(const ushort_t* __restrict__ SbandU, const ushort_t* __restrict__ pvTg,
               const float* __restrict__ O1a, const float* __restrict__ O1b,
               const float* __restrict__ lsum2, const float* __restrict__ clo2,
               const float* __restrict__ chi2, const float* __restrict__ posV,
               ushort_t* __restrict__ athi, ushort_t* __restrict__ atlo)
{
    __shared__ ushort_t pvT[64 * LDPV];   // [d][r] bf16, 33792 B
    const int tid = threadIdx.x;
    const size_t q0 = (size_t)blockIdx.x * 64;
    const int wave = tid >> 6, lane = tid & 63;
    const int w0 = wave >> 1, w1 = wave & 1;
    const int lr = lane & 15, lq = lane >> 4;

    // stage pvT (uint copy, coalesced, conflict-free)
    {
        const unsigned* src = (const unsigned*)pvTg;
        unsigned* dst = (unsigned*)pvT;
        for (int i = tid; i < 64 * LDPV / 2; i += 256) dst[i] = src[i];
    }
    __syncthreads();

    f32x4 acc[2][2];
    #pragma unroll
    for (int i = 0; i < 2; i++)
        #pragma unroll
        for (int j = 0; j < 2; j++)
            acc[i][j] = (f32x4){0.f, 0.f, 0.f, 0.f};

    const ushort_t* bandB = SbandU + q0 * 256;
    #pragma unroll
    for (int kc = 0; kc < 8; kc++) {
        bf16x8 a[2], bv[2];
        #pragma unroll
        for (int i = 0; i < 2; i++) {
            a[i]  = *(const bf16x8*)&bandB[(size_t)(w0*32 + i*16 + lr) * 256 + kc*32 + lq*8];
            bv[i] = *(const bf16x8*)&pvT[(w1*32 + i*16 + lr) * LDPV + kc*32 + lq*8];
        }
        #pragma unroll
        for (int i = 0; i < 2; i++)
            #pragma unroll
            for (int j = 0; j < 2; j++)
                acc[i][j] = __builtin_amdgcn_mfma_f32_16x16x32_bf16(a[i], bv[j], acc[i][j], 0, 0, 0);
    }

    // epilogue: C-layout (row q = quad*4+reg, col d = lr)
    #pragma unroll
    for (int i = 0; i < 2; i++) {
        #pragma unroll
        for (int r = 0; r < 4; r++) {
            const int ql = w0*32 + i*16 + lq*4 + r;
            const size_t gq = q0 + ql;
            const float li = lsum2[gq] + lsum2[GQ_TOT + gq];
            const float cl = clo2[gq]  + clo2[GQ_TOT + gq];
            const float ch = chi2[gq]  + chi2[GQ_TOT + gq];
            const float inv = 1.0f / li;
            const int b  = (int)(gq >> 14);
            const int h  = (int)((gq >> 10) & 15);
            const int lp = (int)(gq & 1023);
            const size_t obase = ((size_t)(b * L_SEQ + lp) * 1024) + h * 64;
            #pragma unroll
            for (int j = 0; j < 2; j++) {
                const int dd = w1*32 + j*16 + lr;
                float o = O1a[gq * DH + dd] + O1b[gq * DH + dd] + acc[i][j][r]
                        + cl * posV[dd] + ch * posV[256 * 64 + dd];
                o *= inv;
                const ushort_t hh = f2bf_rne(o);
                const ushort_t ll = f2bf_rne(o - bf2f(hh));
                athi[obase + dd] = hh;
                atlo[obase + dd] = ll;
            }
        }
    }
}

// ---------------------------------------------------------------------------
extern "C" void kernel_launch(void* const* d_in, const int* in_sizes, int n_in,
                              void* d_out, int out_size, void* d_ws, size_t ws_size,
                              hipStream_t stream)
{
    const float* x    = (const float*)d_in[0];
    const float* pmk  = (const float*)d_in[1];
    const float* Wq   = (const float*)d_in[2];
    const float* bq   = (const float*)d_in[3];
    const float* Wk   = (const float*)d_in[4];
    const float* bk   = (const float*)d_in[5];
    const float* Wv   = (const float*)d_in[6];
    const float* bv   = (const float*)d_in[7];
    const float* Wo   = (const float*)d_in[8];
    const float* bo   = (const float*)d_in[9];
    const float* posK = (const float*)d_in[10];
    const float* posV = (const float*)d_in[11];
    float* out = (float*)d_out;

    // workspace carve-up
    float* ws = (float*)d_ws;
    float* Qb = ws;                                     // GQ*64 f32
    float* Kb = Qb + (size_t)GQ_TOT * DH;
    float* Vb = Kb + (size_t)GQ_TOT * DH;               // V^T per head (mode 2)
    ushort_t* Qpu    = (ushort_t*)(Vb + (size_t)GQ_TOT * DH);   // GQ*260 u16
    ushort_t* SbandU = Qpu + (size_t)GQ_TOT * QP_STRIDE;        // GQ*256 u16
    ushort_t* athi   = SbandU + (size_t)GQ_TOT * 256;           // GQ*64 u16
    ushort_t* atlo   = athi + (size_t)GQ_TOT * DH;
    ushort_t* pvTg   = atlo + (size_t)GQ_TOT * DH;              // 64*LDPV u16
    float* O1a   = (float*)(pvTg + 64 * LDPV);
    float* O1b   = O1a   + (size_t)GQ_TOT * DH;
    float* lsum2 = O1b   + (size_t)GQ_TOT * DH;
    float* clo2  = lsum2 + 2 * (size_t)GQ_TOT;
    float* chi2  = clo2  + 2 * (size_t)GQ_TOT;

    // bf16 scratch aliased into the Sband region (disjoint lifetimes):
    // phase A (x + QKV weight splits, consumed before attn writes bands):
    //   14.68M u16 <= 16.78M region.  phase B (Wo split, after post): 2.1M.
    ushort_t* bb  = SbandU;
    ushort_t* xhi = bb;
    ushort_t* xlo = xhi + 4194304;
    ushort_t* wqh = xlo + 4194304;
    ushort_t* wql = wqh + 1048576;
    ushort_t* wkh = wql + 1048576;
    ushort_t* wkl = wkh + 1048576;
    ushort_t* wvh = wkl + 1048576;
    ushort_t* wvl = wvh + 1048576;
    ushort_t* woh = bb;
    ushort_t* wol = woh + 1048576;

    dim3 tg(16, 16), gg(64, 16), gb(256);

    split_f32<<<dim3(2048), gb, 0, stream>>>(x, xhi, xlo);
    split_transpose<<<tg, gb, 0, stream>>>(Wq, wqh, wql, 1024, 1024);
    split_transpose<<<tg, gb, 0, stream>>>(Wk, wkh, wkl, 1024, 1024);
    split_transpose<<<tg, gb, 0, stream>>>(Wv, wvh, wvl, 1024, 1024);
    prep_pvt<<<dim3(4), gb, 0, stream>>>(posV, pvTg);
    gemm_mfma<<<gg, gb, 0, stream>>>(xhi, xlo, wqh, wql, bq, Qb, 4096, 1024, 1024, 1);
    gemm_mfma<<<gg, gb, 0, stream>>>(xhi, xlo, wkh, wkl, bk, Kb, 4096, 1024, 1024, 1);
    gemm_mfma<<<gg, gb, 0, stream>>>(xhi, xlo, wvh, wvl, bv, Vb, 4096, 1024, 1024, 2);
    qp_kernel<<<dim3(GQ_TOT / 64), gb, 0, stream>>>(Qb, posK, Qpu);
    attn_kernel<<<dim3(2048), gb, 0, stream>>>(Qb, Kb, Vb, Qpu, pmk,
                                               SbandU, O1a, O1b, lsum2, clo2, chi2);
    post_mfma<<<dim3(GQ_TOT / 64), gb, 0, stream>>>(SbandU, pvTg, O1a, O1b, lsum2,
                                                    clo2, chi2, posV, athi, atlo);
    split_transpose<<<tg, gb, 0, stream>>>(Wo, woh, wol, 1024, 1024);
    gemm_mfma<<<gg, gb, 0, stream>>>(athi, atlo, woh, wol, bo, out, 4096, 1024, 1024, 0);
}